// Round 12
// baseline (273.190 us; speedup 1.0000x reference)
//
#include <hip/hip_runtime.h>

#define N_ATOMS 8192
#define DIM 64
#define N_MOL 256
#define KS 16
#define KCH (N_ATOMS / KS)   // 512 k per split
#define BM 64
#define BN 64
#define BK 64
#define NSTEP (KCH / BK)     // 8

typedef __attribute__((ext_vector_type(8))) short short8v;
typedef __attribute__((ext_vector_type(4))) float f32x4;
typedef unsigned char u8;

// async global->LDS, 16B per lane, LDS dest = wave-uniform base + lane*16
__device__ __forceinline__ void gload16(const void* gsrc, void* ldst) {
    __builtin_amdgcn_global_load_lds(
        (const __attribute__((address_space(1))) void*)gsrc,
        (__attribute__((address_space(3))) void*)ldst, 16, 0, 0);
}

__device__ __forceinline__ int lower_bound_dev(const int* __restrict__ seg, int val) {
    int lo = 0, hi = N_ATOMS;
    while (lo < hi) {
        int mid = (lo + hi) >> 1;
        if (seg[mid] < val) lo = mid + 1; else hi = mid;
    }
    return lo;
}

// scale from raw max bits: S = 2^max(ilogb(maxh)-7, 0)  (maxh/S in [128,256) <= 448)
__device__ __forceinline__ float scale_from_raw(int bits) {
    if (bits <= 0) return 1.0f;
    int e = (bits >> 23) - 127 - 7;
    if (e < 0) e = 0;
    return __int_as_float((e + 127) << 23);
}

// ---- streaming convert: A8 = e4m3(A). 268 MB R + 67 MB W, HBM-bound. ----
__global__ __launch_bounds__(256) void convert_kernel(
        const float* __restrict__ A, u8* __restrict__ A8) {
    const size_t total = (size_t)N_ATOMS * N_ATOMS;
    const size_t stride = (size_t)gridDim.x * 256 * 8;
    for (size_t i = ((size_t)blockIdx.x * 256 + threadIdx.x) * 8; i < total; i += stride) {
        float4 a0 = *(const float4*)(A + i);
        float4 a1 = *(const float4*)(A + i + 4);
        int p = __builtin_amdgcn_cvt_pk_fp8_f32(a0.x, a0.y, 0, 0);
        p     = __builtin_amdgcn_cvt_pk_fp8_f32(a0.z, a0.w, p, 1);
        int q = __builtin_amdgcn_cvt_pk_fp8_f32(a1.x, a1.y, 0, 0);
        q     = __builtin_amdgcn_cvt_pk_fp8_f32(a1.z, a1.w, q, 1);
        int2 v; v.x = p; v.y = q;
        *(int2*)(A8 + i) = v;
    }
}

// ---- fused linear: v = (FIRST ? embed : vprev); h = relu(W v + b)
// ---- writes vnext = h (f32) and atomicMax of max|h| into scaleRaw[lay].
template <int FIRST>
__global__ __launch_bounds__(256) void fused_linear_kernel(
        const int* __restrict__ fp, const float* __restrict__ table,
        const float* __restrict__ vprev,
        const float* __restrict__ W, const float* __restrict__ b,
        float* __restrict__ vnext, int* __restrict__ scaleRaw, int lay) {
    __shared__ float Ws[DIM][DIM + 1];
    __shared__ float vsT[DIM][36];

    const int t = threadIdx.x;
    const int n0 = blockIdx.x * 32;
    for (int i = t; i < DIM * DIM; i += 256) Ws[i >> 6][i & 63] = W[i];
    for (int i = t; i < 32 * DIM; i += 256) {
        const int nl = i >> 6, d = i & 63;
        const size_t n = n0 + nl;
        float val;
        if (FIRST) val = table[(size_t)fp[n] * DIM + d];
        else       val = vprev[n * DIM + d];
        vsT[d][nl] = val;
    }
    __syncthreads();

    const int e = t & 63;
    const int g = t >> 6;
    float acc[8];
    const float be = b[e];
#pragma unroll
    for (int i = 0; i < 8; ++i) acc[i] = be;

    for (int d = 0; d < DIM; ++d) {
        const float w = Ws[e][d];
        const float4* vp = (const float4*)&vsT[d][g * 8];
        float4 x0 = vp[0], x1 = vp[1];
        acc[0] += w * x0.x; acc[1] += w * x0.y; acc[2] += w * x0.z; acc[3] += w * x0.w;
        acc[4] += w * x1.x; acc[5] += w * x1.y; acc[6] += w * x1.z; acc[7] += w * x1.w;
    }

    float hmax = 0.f;
#pragma unroll
    for (int i = 0; i < 8; ++i) {
        float hv = acc[i] > 0.f ? acc[i] : 0.f;
        vnext[(size_t)(n0 + g * 8 + i) * DIM + e] = hv;
        hmax = hv > hmax ? hv : hmax;
    }
    atomicMax(scaleRaw + lay, __float_as_int(hmax));   // h >= 0: int order == float order
}

// ---- pack: hT8[hi/lo][e][n] from h f32 (scaled hi+lo e4m3 split) ----
__global__ __launch_bounds__(256) void pack_kernel(
        const float* __restrict__ h, const int* __restrict__ scaleRaw, int lay,
        u8* __restrict__ hT8) {
    const float invS = 1.0f / scale_from_raw(scaleRaw[lay]);
    const int t = threadIdx.x;
    const int e = t & 63;
    const int g = t >> 6;
    const int nb = blockIdx.x * 32 + g * 8;

    float y[8];
#pragma unroll
    for (int i = 0; i < 8; ++i) y[i] = h[(size_t)(nb + i) * DIM + e] * invS;

    int hp0 = __builtin_amdgcn_cvt_pk_fp8_f32(y[0], y[1], 0, 0);
    hp0     = __builtin_amdgcn_cvt_pk_fp8_f32(y[2], y[3], hp0, 1);
    int hp1 = __builtin_amdgcn_cvt_pk_fp8_f32(y[4], y[5], 0, 0);
    hp1     = __builtin_amdgcn_cvt_pk_fp8_f32(y[6], y[7], hp1, 1);

    // residuals: builtin's lane-select must be a literal constant -> hand-unrolled
    float r[8];
    r[0] = y[0] - __builtin_amdgcn_cvt_f32_fp8(hp0, 0);
    r[1] = y[1] - __builtin_amdgcn_cvt_f32_fp8(hp0, 1);
    r[2] = y[2] - __builtin_amdgcn_cvt_f32_fp8(hp0, 2);
    r[3] = y[3] - __builtin_amdgcn_cvt_f32_fp8(hp0, 3);
    r[4] = y[4] - __builtin_amdgcn_cvt_f32_fp8(hp1, 0);
    r[5] = y[5] - __builtin_amdgcn_cvt_f32_fp8(hp1, 1);
    r[6] = y[6] - __builtin_amdgcn_cvt_f32_fp8(hp1, 2);
    r[7] = y[7] - __builtin_amdgcn_cvt_f32_fp8(hp1, 3);

    int lp0 = __builtin_amdgcn_cvt_pk_fp8_f32(r[0], r[1], 0, 0);
    lp0     = __builtin_amdgcn_cvt_pk_fp8_f32(r[2], r[3], lp0, 1);
    int lp1 = __builtin_amdgcn_cvt_pk_fp8_f32(r[4], r[5], 0, 0);
    lp1     = __builtin_amdgcn_cvt_pk_fp8_f32(r[6], r[7], lp1, 1);

    int2 hv; hv.x = hp0; hv.y = hp1;
    int2 lv; lv.x = lp0; lv.y = lp1;
    *(int2*)(hT8 + (size_t)e * N_ATOMS + nb) = hv;                            // hi plane
    *(int2*)(hT8 + (size_t)DIM * N_ATOMS + (size_t)e * N_ATOMS + nb) = lv;    // lo plane
}

// ---- vnext += S * (A8[rows,ksplit] @ (hi+lo))  — fp8 MFMA, counted-vmcnt (r10).
// LDS rows 64B (fp8): chunk s (16B, 4/row) stored at s ^ (row&3); linear dest +
// inverse-swizzled global source (rule #21). 3 gload16/thread/stage -> vmcnt(3).
__global__ __launch_bounds__(256) void matmul_mfma_kernel(
        const u8* __restrict__ A8, const u8* __restrict__ hT8,
        const int* __restrict__ scaleRaw, int lay, float* __restrict__ vnext) {
    __shared__ __align__(16) u8 Asw[2][BM * BK];   // 2 x 4 KB
    __shared__ __align__(16) u8 Bhi[2][BN * BK];   // 2 x 4 KB
    __shared__ __align__(16) u8 Blo[2][BN * BK];   // 2 x 4 KB

    const int t  = threadIdx.x;
    const int w  = t >> 6;
    const int l  = t & 63;
    const int lm = l & 15;
    const int lq = l >> 4;
    const int r0 = blockIdx.x * BM;
    const size_t kc0 = (size_t)blockIdx.y * KCH;
    const u8* hlo = hT8 + (size_t)DIM * N_ATOMS;

    auto stage = [&](int bi, size_t kb) {
        // thread t: row r = t>>2 (0..63), chunk s = t&3; dest linear [r][s]
        const int r = t >> 2, s = t & 3;
        const int src_off = ((s ^ (r & 3)) << 4);
        gload16(A8 + (size_t)(r0 + r) * N_ATOMS + kb + src_off,
                &Asw[bi][(w * 64) * 16]);
        gload16(hT8 + (size_t)r * N_ATOMS + kb + src_off,
                &Bhi[bi][(w * 64) * 16]);
        gload16(hlo + (size_t)r * N_ATOMS + kb + src_off,
                &Blo[bi][(w * 64) * 16]);
    };

    f32x4 acc[4];
#pragma unroll
    for (int n = 0; n < 4; ++n) acc[n] = (f32x4){0.f, 0.f, 0.f, 0.f};

    stage(0, kc0);   // 3 loads in flight

    for (int ks = 0; ks < NSTEP; ++ks) {
        const int bi = ks & 1;
        if (ks + 1 < NSTEP) {
            stage(bi ^ 1, kc0 + (size_t)(ks + 1) * BK);
            asm volatile("s_waitcnt vmcnt(3)" ::: "memory");  // cur tile's 3 done
        } else {
            asm volatile("s_waitcnt vmcnt(0)" ::: "memory");
        }
        __builtin_amdgcn_s_barrier();                         // buf[bi] readable
        asm volatile("" ::: "memory");
#pragma unroll
        for (int kki = 0; kki < 2; ++kki) {
            // lane reads 8B at logical byte k = kki*32 + lq*8 of its row
            const int klog = kki * 2 + (lq >> 1);             // 16B chunk index
            const int within = (lq & 1) * 8;
            const int ra = w * 16 + lm;
            const long a = *(const long*)&Asw[bi][ra * BK + ((klog ^ (ra & 3)) << 4) + within];
#pragma unroll
            for (int n = 0; n < 4; ++n) {
                const int rb = n * 16 + lm;
                const int off = rb * BK + ((klog ^ (rb & 3)) << 4) + within;
                const long bh = *(const long*)&Bhi[bi][off];
                const long bl = *(const long*)&Blo[bi][off];
                acc[n] = __builtin_amdgcn_mfma_f32_16x16x32_fp8_fp8(a, bh, acc[n], 0, 0, 0);
                acc[n] = __builtin_amdgcn_mfma_f32_16x16x32_fp8_fp8(a, bl, acc[n], 0, 0, 0);
            }
        }
        asm volatile("" ::: "memory");
        __builtin_amdgcn_s_barrier();                         // reads of buf[bi] done
        asm volatile("" ::: "memory");
    }

    const float S = scale_from_raw(scaleRaw[lay]);
    // C/D layout: col = lane&15, row = (lane>>4)*4 + reg  [m89; dtype-independent]
    const int rb = r0 + w * 16 + lq * 4;
#pragma unroll
    for (int j = 0; j < 4; ++j) {
        float* vp = vnext + (size_t)(rb + j) * DIM + lm;
#pragma unroll
        for (int n = 0; n < 4; ++n) atomicAdd(vp + n * 16, acc[n][j] * S);
    }
}

// ------ segment sum: out[m][d] = sum_{n: seg[n]==m} v[n][d] ------
__global__ __launch_bounds__(256) void segsum_kernel(
        const float* __restrict__ v, const int* __restrict__ seg,
        float* __restrict__ out) {
    __shared__ float sm[4][DIM];
    const int m = blockIdx.x;
    const int d = threadIdx.x & 63;
    const int g = threadIdx.x >> 6;
    const int lo = lower_bound_dev(seg, m);
    const int hi = lower_bound_dev(seg, m + 1);
    float acc = 0.f;
    for (int n = lo + g; n < hi; n += 4) acc += v[(size_t)n * DIM + d];
    sm[g][d] = acc;
    __syncthreads();
    if (g == 0) out[(size_t)m * DIM + d] = sm[0][d] + sm[1][d] + sm[2][d] + sm[3][d];
}

extern "C" void kernel_launch(void* const* d_in, const int* in_sizes, int n_in,
                              void* d_out, int out_size, void* d_ws, size_t ws_size,
                              hipStream_t stream) {
    const int*   fp    = (const int*)d_in[0];
    const float* A     = (const float*)d_in[1];
    const int*   seg   = (const int*)d_in[2];
    const float* table = (const float*)d_in[3];
    const float* W     = (const float*)d_in[4];
    const float* b     = (const float*)d_in[5];
    float* out = (float*)d_out;

    char* ws = (char*)d_ws;
    float* vA       = (float*)ws;                                   // 2 MB
    float* vB       = (float*)(ws + (size_t)2 * 1024 * 1024);       // 2 MB
    u8*    hT8      = (u8*)   (ws + (size_t)4 * 1024 * 1024);       // 1 MB (hi+lo)
    int*   scaleRaw = (int*)  (ws + (size_t)5 * 1024 * 1024);       // 16 B
    u8*    A8       = (u8*)   (ws + (size_t)5 * 1024 * 1024 + 256); // 67 MB

    (void)hipMemsetAsync(scaleRaw, 0, 4 * sizeof(int), stream);
    convert_kernel<<<2048, 256, 0, stream>>>(A, A8);

    dim3 mmgrid(N_ATOMS / BM, KS);

    // layer 0
    fused_linear_kernel<1><<<N_ATOMS / 32, 256, 0, stream>>>(
        fp, table, nullptr, W, b, vA, scaleRaw, 0);
    pack_kernel<<<N_ATOMS / 32, 256, 0, stream>>>(vA, scaleRaw, 0, hT8);
    matmul_mfma_kernel<<<mmgrid, 256, 0, stream>>>(A8, hT8, scaleRaw, 0, vA);
    // layer 1
    fused_linear_kernel<0><<<N_ATOMS / 32, 256, 0, stream>>>(
        fp, table, vA, W + DIM * DIM, b + DIM, vB, scaleRaw, 1);
    pack_kernel<<<N_ATOMS / 32, 256, 0, stream>>>(vB, scaleRaw, 1, hT8);
    matmul_mfma_kernel<<<mmgrid, 256, 0, stream>>>(A8, hT8, scaleRaw, 1, vB);
    // layer 2
    fused_linear_kernel<0><<<N_ATOMS / 32, 256, 0, stream>>>(
        fp, table, vB, W + 2 * DIM * DIM, b + 2 * DIM, vA, scaleRaw, 2);
    pack_kernel<<<N_ATOMS / 32, 256, 0, stream>>>(vA, scaleRaw, 2, hT8);
    matmul_mfma_kernel<<<mmgrid, 256, 0, stream>>>(A8, hT8, scaleRaw, 2, vA);
    // pooled output
    segsum_kernel<<<N_MOL, 256, 0, stream>>>(vA, seg, out);
}

// Round 13
// 218.724 us; speedup vs baseline: 1.2490x; 1.2490x over previous
//
#include <hip/hip_runtime.h>

#define N_ATOMS 8192
#define DIM 64
#define N_MOL 256
#define KS 16
#define KCH (N_ATOMS / KS)   // 512 k per split
#define BM 64
#define BN 64
#define BK 64
#define NSTEP (KCH / BK)     // 8

typedef __attribute__((ext_vector_type(8))) short short8v;
typedef __attribute__((ext_vector_type(4))) float f32x4;
typedef unsigned short ushort_t;

// f32 -> bf16 RTNE (inputs finite)
__device__ __forceinline__ ushort_t f2bf(float x) {
    unsigned u = __float_as_uint(x);
    u += 0x7fffu + ((u >> 16) & 1u);
    return (ushort_t)(u >> 16);
}

// async global->LDS, 16B per lane, LDS dest = wave-uniform base + lane*16
__device__ __forceinline__ void gload16(const void* gsrc, void* ldst) {
    __builtin_amdgcn_global_load_lds(
        (const __attribute__((address_space(1))) void*)gsrc,
        (__attribute__((address_space(3))) void*)ldst, 16, 0, 0);
}

// ---- fused convert + S*A: one pass over A (268 MB).
// Abf = bf16(A); SAf32[m][k] += sum_{n in seg m} A[n][k] (<=2 atomic contribs
// per (m,k) since molecules (avg 32 rows) span <=2 row-chunks of 128 -> the
// f32 add commutes bitwise => deterministic).
// grid (8192/512 = 16 colchunks, 8192/128 = 64 rowchunks), 256 thr, 2 cols/thr.
__global__ __launch_bounds__(256) void convsa_kernel(
        const float* __restrict__ A, const int* __restrict__ seg,
        ushort_t* __restrict__ Abf, float* __restrict__ SAf32) {
    const int t = threadIdx.x;
    const int k = blockIdx.x * 512 + t * 2;
    const int n0 = blockIdx.y * 128;
    __shared__ int segs[128];
    if (t < 128) segs[t] = seg[n0 + t];
    __syncthreads();

    float a0 = 0.f, a1 = 0.f;
    int prev = segs[0];
    for (int ni = 0; ni < 128; ni += 4) {
        // 4 independent row loads in flight, then uniform-branch scan
        float2 v0 = *(const float2*)(A + (size_t)(n0 + ni + 0) * N_ATOMS + k);
        float2 v1 = *(const float2*)(A + (size_t)(n0 + ni + 1) * N_ATOMS + k);
        float2 v2 = *(const float2*)(A + (size_t)(n0 + ni + 2) * N_ATOMS + k);
        float2 v3 = *(const float2*)(A + (size_t)(n0 + ni + 3) * N_ATOMS + k);
        float2 vs[4] = {v0, v1, v2, v3};
#pragma unroll
        for (int j = 0; j < 4; ++j) {
            const int m = segs[ni + j];
            if (m != prev) {   // uniform across block
                atomicAdd(&SAf32[(size_t)prev * N_ATOMS + k],     a0);
                atomicAdd(&SAf32[(size_t)prev * N_ATOMS + k + 1], a1);
                a0 = a1 = 0.f; prev = m;
            }
            ushort2 bv; bv.x = f2bf(vs[j].x); bv.y = f2bf(vs[j].y);
            *(ushort2*)(Abf + (size_t)(n0 + ni + j) * N_ATOMS + k) = bv;
            a0 += vs[j].x; a1 += vs[j].y;
        }
    }
    atomicAdd(&SAf32[(size_t)prev * N_ATOMS + k],     a0);
    atomicAdd(&SAf32[(size_t)prev * N_ATOMS + k + 1], a1);
}

// ---- pack SAf32 -> SAbf (bf16, dense 256 x 8192, row stride N_ATOMS) ----
__global__ __launch_bounds__(256) void packsa_kernel(
        const float* __restrict__ SAf32, ushort_t* __restrict__ SAbf) {
    const size_t i = ((size_t)blockIdx.x * 256 + threadIdx.x) * 8;
    float4 x0 = *(const float4*)(SAf32 + i);
    float4 x1 = *(const float4*)(SAf32 + i + 4);
    short8v v;
    v[0] = (short)f2bf(x0.x); v[1] = (short)f2bf(x0.y);
    v[2] = (short)f2bf(x0.z); v[3] = (short)f2bf(x0.w);
    v[4] = (short)f2bf(x1.x); v[5] = (short)f2bf(x1.y);
    v[6] = (short)f2bf(x1.z); v[7] = (short)f2bf(x1.w);
    *(short8v*)(SAbf + i) = v;
}

// ---- fused linear: v = (FIRST ? embed : vprev); h = relu(W v + b)
// writes hT (bf16 [DIM][N_ATOMS]); if !LAST writes vnext = h (f32);
// if LAST instead accumulates segsum(h) into out via scan+atomicAdd.
template <int FIRST, int LAST>
__global__ __launch_bounds__(256) void fused_linear_kernel(
        const int* __restrict__ fp, const float* __restrict__ table,
        const float* __restrict__ vprev, const int* __restrict__ seg,
        const float* __restrict__ W, const float* __restrict__ b,
        float* __restrict__ vnext, ushort_t* __restrict__ hT,
        float* __restrict__ out) {
    __shared__ float Ws[DIM][DIM + 1];
    __shared__ float vsT[DIM][36];
    __shared__ int segs[32];

    const int t = threadIdx.x;
    const int n0 = blockIdx.x * 32;
    if (LAST && t < 32) segs[t] = seg[n0 + t];
    for (int i = t; i < DIM * DIM; i += 256) Ws[i >> 6][i & 63] = W[i];
    for (int i = t; i < 32 * DIM; i += 256) {
        const int nl = i >> 6, d = i & 63;
        const size_t n = n0 + nl;
        float val;
        if (FIRST) val = table[(size_t)fp[n] * DIM + d];
        else       val = vprev[n * DIM + d];
        vsT[d][nl] = val;
    }
    __syncthreads();

    const int e = t & 63;
    const int g = t >> 6;
    float acc[8];
    const float be = b[e];
#pragma unroll
    for (int i = 0; i < 8; ++i) acc[i] = be;

    for (int d = 0; d < DIM; ++d) {
        const float w = Ws[e][d];
        const float4* vp = (const float4*)&vsT[d][g * 8];
        float4 x0 = vp[0], x1 = vp[1];
        acc[0] += w * x0.x; acc[1] += w * x0.y; acc[2] += w * x0.z; acc[3] += w * x0.w;
        acc[4] += w * x1.x; acc[5] += w * x1.y; acc[6] += w * x1.z; acc[7] += w * x1.w;
    }

    ushort_t hb[8];
    float seg_acc = 0.f;
    int prev = LAST ? segs[g * 8] : 0;
#pragma unroll
    for (int i = 0; i < 8; ++i) {
        float hv = acc[i] > 0.f ? acc[i] : 0.f;
        if (LAST) {
            const int m = segs[g * 8 + i];
            if (m != prev) {
                atomicAdd(&out[(size_t)prev * DIM + e], seg_acc);
                seg_acc = 0.f; prev = m;
            }
            seg_acc += hv;
        } else {
            vnext[(size_t)(n0 + g * 8 + i) * DIM + e] = hv;
        }
        hb[i] = f2bf(hv);
    }
    if (LAST) atomicAdd(&out[(size_t)prev * DIM + e], seg_acc);
    *(short8v*)(hT + (size_t)e * N_ATOMS + n0 + g * 8) = *(short8v*)&hb[0];
}

// ---- vnext += Arows[ , ksplit] @ h  — BM=64, counted-vmcnt pipeline (r10).
// grid (rows/BM, KS), 256 threads = 4 waves; wave w: rows w*16..+16, cols 0..64.
// LDS: tile[row][slot], slot s (16B) at s ^ (row&7); linear dest + inverse-
// swizzled global source (rule #21). 4 gload16/thread/stage -> vmcnt(4).
__global__ __launch_bounds__(256) void matmul_mfma_kernel(
        const ushort_t* __restrict__ Abf, const ushort_t* __restrict__ hT,
        float* __restrict__ vnext) {
    __shared__ ushort_t Asw[2][BM * BK];   // 2 x 8 KB
    __shared__ ushort_t Bsw[2][BN * BK];   // 2 x 8 KB

    const int t  = threadIdx.x;
    const int w  = t >> 6;
    const int l  = t & 63;
    const int lm = l & 15;
    const int lq = l >> 4;
    const int r0 = blockIdx.x * BM;
    const size_t kc0 = (size_t)blockIdx.y * KCH;

    auto stage = [&](int bi, size_t kb) {
#pragma unroll
        for (int q = 0; q < 2; ++q) {
            const int i = q * 256 + t;
            const int r = i >> 3, s = i & 7;
            gload16(Abf + (size_t)(r0 + r) * N_ATOMS + kb + ((s ^ (r & 7)) << 3),
                    &Asw[bi][(q * 256 + w * 64) * 8]);
        }
#pragma unroll
        for (int q = 0; q < 2; ++q) {
            const int i = q * 256 + t;
            const int r = i >> 3, s = i & 7;
            gload16(hT + (size_t)r * N_ATOMS + kb + ((s ^ (r & 7)) << 3),
                    &Bsw[bi][(q * 256 + w * 64) * 8]);
        }
    };

    f32x4 acc[4];
#pragma unroll
    for (int n = 0; n < 4; ++n) acc[n] = (f32x4){0.f, 0.f, 0.f, 0.f};

    stage(0, kc0);   // 4 loads in flight

    for (int ks = 0; ks < NSTEP; ++ks) {
        const int bi = ks & 1;
        if (ks + 1 < NSTEP) {
            stage(bi ^ 1, kc0 + (size_t)(ks + 1) * BK);       // +4 newest
            asm volatile("s_waitcnt vmcnt(4)" ::: "memory");  // cur's 4 done
        } else {
            asm volatile("s_waitcnt vmcnt(0)" ::: "memory");
        }
        __builtin_amdgcn_s_barrier();                         // buf[bi] readable
        asm volatile("" ::: "memory");
#pragma unroll
        for (int kki = 0; kki < 2; ++kki) {
            const int sx = ((kki * 4 + lq) ^ (lm & 7)) << 3;
            const int ra = w * 16 + lm;
            short8v a0 = *(const short8v*)&Asw[bi][ra * BK + sx];
            short8v b0 = *(const short8v*)&Bsw[bi][(lm)      * BK + sx];
            short8v b1 = *(const short8v*)&Bsw[bi][(lm + 16) * BK + sx];
            short8v b2 = *(const short8v*)&Bsw[bi][(lm + 32) * BK + sx];
            short8v b3 = *(const short8v*)&Bsw[bi][(lm + 48) * BK + sx];
            acc[0] = __builtin_amdgcn_mfma_f32_16x16x32_bf16(a0, b0, acc[0], 0, 0, 0);
            acc[1] = __builtin_amdgcn_mfma_f32_16x16x32_bf16(a0, b1, acc[1], 0, 0, 0);
            acc[2] = __builtin_amdgcn_mfma_f32_16x16x32_bf16(a0, b2, acc[2], 0, 0, 0);
            acc[3] = __builtin_amdgcn_mfma_f32_16x16x32_bf16(a0, b3, acc[3], 0, 0, 0);
        }
        asm volatile("" ::: "memory");
        __builtin_amdgcn_s_barrier();                         // reads of buf[bi] done
        asm volatile("" ::: "memory");
    }

    // C/D layout: col = lane&15, row = (lane>>4)*4 + reg  [m89 verified]
    const int rb = r0 + w * 16 + lq * 4;
#pragma unroll
    for (int j = 0; j < 4; ++j) {
        float* vp = vnext + (size_t)(rb + j) * DIM + lm;
#pragma unroll
        for (int n = 0; n < 4; ++n) atomicAdd(vp + n * 16, acc[n][j]);
    }
}

extern "C" void kernel_launch(void* const* d_in, const int* in_sizes, int n_in,
                              void* d_out, int out_size, void* d_ws, size_t ws_size,
                              hipStream_t stream) {
    const int*   fp    = (const int*)d_in[0];
    const float* A     = (const float*)d_in[1];
    const int*   seg   = (const int*)d_in[2];
    const float* table = (const float*)d_in[3];
    const float* W     = (const float*)d_in[4];
    const float* b     = (const float*)d_in[5];
    float* out = (float*)d_out;

    char* ws = (char*)d_ws;
    float*    vA    = (float*)    ws;                         // 2 MB
    float*    vB    = (float*)   (ws + 2097152);              // 2 MB
    ushort_t* hT    = (ushort_t*)(ws + 4194304);              // 1 MB
    float*    SAf32 = (float*)   (ws + 5242880);              // 8 MB
    ushort_t* SAbf  = (ushort_t*)(ws + 13631488);             // 4 MB
    ushort_t* Abf   = (ushort_t*)(ws + 17825792);             // 134 MB

    (void)hipMemsetAsync(SAf32, 0, (size_t)N_MOL * N_ATOMS * 4, stream);
    (void)hipMemsetAsync(out, 0, (size_t)out_size * 4, stream);

    // one pass over A: bf16 copy + S*A row-segment sums
    convsa_kernel<<<dim3(16, 64), 256, 0, stream>>>(A, seg, Abf, SAf32);
    packsa_kernel<<<(N_MOL * N_ATOMS) / (256 * 8), 256, 0, stream>>>(SAf32, SAbf);

    dim3 mmgrid(N_ATOMS / BM, KS);

    // layer 0: vA = h0, vA += A@h0
    fused_linear_kernel<1, 0><<<N_ATOMS / 32, 256, 0, stream>>>(
        fp, table, nullptr, seg, W, b, vA, hT, nullptr);
    matmul_mfma_kernel<<<mmgrid, 256, 0, stream>>>(Abf, hT, vA);
    // layer 1: vB = h1, vB += A@h1
    fused_linear_kernel<0, 0><<<N_ATOMS / 32, 256, 0, stream>>>(
        fp, table, vA, seg, W + DIM * DIM, b + DIM, vB, hT, nullptr);
    matmul_mfma_kernel<<<mmgrid, 256, 0, stream>>>(Abf, hT, vB);
    // layer 2: h2 -> hT + segsum(h2) atomically into out (no v write)
    fused_linear_kernel<0, 1><<<N_ATOMS / 32, 256, 0, stream>>>(
        fp, table, vB, seg, W + 2 * DIM * DIM, b + 2 * DIM, nullptr, hT, out);
    // telescoped final matmul: out += (S*A) @ h2  (validated GEMM on 256 rows)
    matmul_mfma_kernel<<<dim3(N_MOL / BM, KS), 256, 0, stream>>>(SAbf, hT, out);
}

// Round 14
// 191.759 us; speedup vs baseline: 1.4247x; 1.1406x over previous
//
#include <hip/hip_runtime.h>

#define N_ATOMS 8192
#define DIM 64
#define N_MOL 256
#define KS 16
#define KCH (N_ATOMS / KS)   // 512 k per split
#define BM 64
#define BN 64
#define BK 64
#define NSTEP (KCH / BK)     // 8

typedef __attribute__((ext_vector_type(8))) short short8v;
typedef __attribute__((ext_vector_type(4))) float f32x4;
typedef unsigned short ushort_t;

// f32 -> bf16 RTNE (inputs finite)
__device__ __forceinline__ ushort_t f2bf(float x) {
    unsigned u = __float_as_uint(x);
    u += 0x7fffu + ((u >> 16) & 1u);
    return (ushort_t)(u >> 16);
}
__device__ __forceinline__ float bf2f(ushort_t u) {
    return __uint_as_float(((unsigned)u) << 16);
}

// async global->LDS, 16B per lane, LDS dest = wave-uniform base + lane*16
__device__ __forceinline__ void gload16(const void* gsrc, void* ldst) {
    __builtin_amdgcn_global_load_lds(
        (const __attribute__((address_space(1))) void*)gsrc,
        (__attribute__((address_space(3))) void*)ldst, 16, 0, 0);
}

// ---- pack SAf32 -> SAbf (bf16, dense 256 x 8192, row stride N_ATOMS) ----
__global__ __launch_bounds__(256) void packsa_kernel(
        const float* __restrict__ SAf32, ushort_t* __restrict__ SAbf) {
    const size_t i = ((size_t)blockIdx.x * 256 + threadIdx.x) * 8;
    float4 x0 = *(const float4*)(SAf32 + i);
    float4 x1 = *(const float4*)(SAf32 + i + 4);
    short8v v;
    v[0] = (short)f2bf(x0.x); v[1] = (short)f2bf(x0.y);
    v[2] = (short)f2bf(x0.z); v[3] = (short)f2bf(x0.w);
    v[4] = (short)f2bf(x1.x); v[5] = (short)f2bf(x1.y);
    v[6] = (short)f2bf(x1.z); v[7] = (short)f2bf(x1.w);
    *(short8v*)(SAbf + i) = v;
}

// ---- fused linear: v = (FIRST ? embed : vprev); h = relu(W v + b)
// writes hT (bf16 [DIM][N_ATOMS]); if !LAST writes vnext = h (f32);
// if LAST instead accumulates segsum(h) into out via scan+atomicAdd.
template <int FIRST, int LAST>
__global__ __launch_bounds__(256) void fused_linear_kernel(
        const int* __restrict__ fp, const float* __restrict__ table,
        const float* __restrict__ vprev, const int* __restrict__ seg,
        const float* __restrict__ W, const float* __restrict__ b,
        float* __restrict__ vnext, ushort_t* __restrict__ hT,
        float* __restrict__ out) {
    __shared__ float Ws[DIM][DIM + 1];
    __shared__ float vsT[DIM][36];
    __shared__ int segs[32];

    const int t = threadIdx.x;
    const int n0 = blockIdx.x * 32;
    if (LAST && t < 32) segs[t] = seg[n0 + t];
    for (int i = t; i < DIM * DIM; i += 256) Ws[i >> 6][i & 63] = W[i];
    for (int i = t; i < 32 * DIM; i += 256) {
        const int nl = i >> 6, d = i & 63;
        const size_t n = n0 + nl;
        float val;
        if (FIRST) val = table[(size_t)fp[n] * DIM + d];
        else       val = vprev[n * DIM + d];
        vsT[d][nl] = val;
    }
    __syncthreads();

    const int e = t & 63;
    const int g = t >> 6;
    float acc[8];
    const float be = b[e];
#pragma unroll
    for (int i = 0; i < 8; ++i) acc[i] = be;

    for (int d = 0; d < DIM; ++d) {
        const float w = Ws[e][d];
        const float4* vp = (const float4*)&vsT[d][g * 8];
        float4 x0 = vp[0], x1 = vp[1];
        acc[0] += w * x0.x; acc[1] += w * x0.y; acc[2] += w * x0.z; acc[3] += w * x0.w;
        acc[4] += w * x1.x; acc[5] += w * x1.y; acc[6] += w * x1.z; acc[7] += w * x1.w;
    }

    ushort_t hb[8];
    float seg_acc = 0.f;
    int prev = LAST ? segs[g * 8] : 0;
#pragma unroll
    for (int i = 0; i < 8; ++i) {
        float hv = acc[i] > 0.f ? acc[i] : 0.f;
        if (LAST) {
            const int m = segs[g * 8 + i];
            if (m != prev) {
                atomicAdd(&out[(size_t)prev * DIM + e], seg_acc);
                seg_acc = 0.f; prev = m;
            }
            seg_acc += hv;
        } else {
            vnext[(size_t)(n0 + g * 8 + i) * DIM + e] = hv;
        }
        hb[i] = f2bf(hv);
    }
    if (LAST) atomicAdd(&out[(size_t)prev * DIM + e], seg_acc);
    *(short8v*)(hT + (size_t)e * N_ATOMS + n0 + g * 8) = *(short8v*)&hb[0];
}

// ---- layer-0 mega kernel: one pass over f32 A per (row,k) chunk:
//   vnext += A@h0 (MFMA), Abf = bf16(A), SAf32[m][k] += segment col-sums.
// Reg-staged CVT (r8-validated), counted-vmcnt schedule (r10-validated).
// grid (N_ATOMS/BM, KS), 256 thr = 4 waves.
__global__ __launch_bounds__(256) void matmul_cvtsa_kernel(
        const float* __restrict__ A, const int* __restrict__ seg,
        ushort_t* __restrict__ Abf, float* __restrict__ SAf32,
        const ushort_t* __restrict__ hT, float* __restrict__ vnext) {
    __shared__ ushort_t Asw[2][BM * BK];   // 2 x 8 KB
    __shared__ ushort_t Bsw[2][BN * BK];   // 2 x 8 KB
    __shared__ int segs[BM];

    const int t  = threadIdx.x;
    const int w  = t >> 6;
    const int l  = t & 63;
    const int lm = l & 15;
    const int lq = l >> 4;
    const int r0 = blockIdx.x * BM;
    const size_t kc0 = (size_t)blockIdx.y * KCH;

    if (t < BM) segs[t] = seg[r0 + t];

    // reg-staged A (f32 -> bf16 -> swizzled ds_write + Abf store) + gload B
    auto stage = [&](int bi, size_t kb) {
#pragma unroll
        for (int q = 0; q < 2; ++q) {
            const int i = q * 256 + t;
            const int r = i >> 3, s = i & 7;
            const size_t goff = (size_t)(r0 + r) * N_ATOMS + kb + s * 8;
            const float4* g = (const float4*)(A + goff);
            float4 a0 = g[0], a1 = g[1];
            short8v vv;
            vv[0] = (short)f2bf(a0.x); vv[1] = (short)f2bf(a0.y);
            vv[2] = (short)f2bf(a0.z); vv[3] = (short)f2bf(a0.w);
            vv[4] = (short)f2bf(a1.x); vv[5] = (short)f2bf(a1.y);
            vv[6] = (short)f2bf(a1.z); vv[7] = (short)f2bf(a1.w);
            *(short8v*)&Asw[bi][r * BK + ((s ^ (r & 7)) << 3)] = vv;
            *(short8v*)(Abf + goff) = vv;
        }
#pragma unroll
        for (int q = 0; q < 2; ++q) {
            const int i = q * 256 + t;
            const int r = i >> 3, s = i & 7;
            gload16(hT + (size_t)r * N_ATOMS + kb + ((s ^ (r & 7)) << 3),
                    &Bsw[bi][(q * 256 + w * 64) * 8]);
        }
    };

    f32x4 acc[4];
#pragma unroll
    for (int n = 0; n < 4; ++n) acc[n] = (f32x4){0.f, 0.f, 0.f, 0.f};

    stage(0, kc0);   // 2 B-gloads in flight (A reg-loads drained by ds_write dep)

    for (int ks = 0; ks < NSTEP; ++ks) {
        const int bi = ks & 1;
        if (ks + 1 < NSTEP) {
            stage(bi ^ 1, kc0 + (size_t)(ks + 1) * BK);
            // <=2 outstanding vmem => current tile's B gloads (older) done.
            asm volatile("s_waitcnt vmcnt(2) lgkmcnt(0)" ::: "memory");
        } else {
            asm volatile("s_waitcnt vmcnt(0) lgkmcnt(0)" ::: "memory");
        }
        __builtin_amdgcn_s_barrier();                         // B1: buf[bi] readable
        asm volatile("" ::: "memory");
        // ---- MFMA phase ----
#pragma unroll
        for (int kki = 0; kki < 2; ++kki) {
            const int sx = ((kki * 4 + lq) ^ (lm & 7)) << 3;
            const int ra = w * 16 + lm;
            short8v a0 = *(const short8v*)&Asw[bi][ra * BK + sx];
            short8v b0 = *(const short8v*)&Bsw[bi][(lm)      * BK + sx];
            short8v b1 = *(const short8v*)&Bsw[bi][(lm + 16) * BK + sx];
            short8v b2 = *(const short8v*)&Bsw[bi][(lm + 32) * BK + sx];
            short8v b3 = *(const short8v*)&Bsw[bi][(lm + 48) * BK + sx];
            acc[0] = __builtin_amdgcn_mfma_f32_16x16x32_bf16(a0, b0, acc[0], 0, 0, 0);
            acc[1] = __builtin_amdgcn_mfma_f32_16x16x32_bf16(a0, b1, acc[1], 0, 0, 0);
            acc[2] = __builtin_amdgcn_mfma_f32_16x16x32_bf16(a0, b2, acc[2], 0, 0, 0);
            acc[3] = __builtin_amdgcn_mfma_f32_16x16x32_bf16(a0, b3, acc[3], 0, 0, 0);
        }
        // ---- SA phase: wave w scans rows w*16..+16 of col c = t&63 ----
        {
            const int c  = t & 63;
            const int cs = c >> 3, cj = c & 7;
            const int kglob = (int)kc0 + ks * BK + c;
            float sacc = 0.f;
            int prev = segs[w * 16];
#pragma unroll
            for (int rr = 0; rr < 16; ++rr) {
                const int row = w * 16 + rr;
                const int m = segs[row];              // uniform within wave
                if (m != prev) {
                    atomicAdd(&SAf32[(size_t)prev * N_ATOMS + kglob], sacc);
                    sacc = 0.f; prev = m;
                }
                sacc += bf2f(Asw[bi][row * BK + ((cs ^ (row & 7)) << 3) + cj]);
            }
            atomicAdd(&SAf32[(size_t)prev * N_ATOMS + kglob], sacc);
        }
        asm volatile("" ::: "memory");
        __builtin_amdgcn_s_barrier();                         // B2: reads of buf[bi] done
        asm volatile("" ::: "memory");
    }

    // C/D layout: col = lane&15, row = (lane>>4)*4 + reg  [m89 verified]
    const int rb = r0 + w * 16 + lq * 4;
#pragma unroll
    for (int j = 0; j < 4; ++j) {
        float* vp = vnext + (size_t)(rb + j) * DIM + lm;
#pragma unroll
        for (int n = 0; n < 4; ++n) atomicAdd(vp + n * 16, acc[n][j]);
    }
}

// ---- vnext += Arows[ , ksplit] @ h  — r10/r13 verbatim (counted vmcnt) ----
__global__ __launch_bounds__(256) void matmul_mfma_kernel(
        const ushort_t* __restrict__ Abf, const ushort_t* __restrict__ hT,
        float* __restrict__ vnext) {
    __shared__ ushort_t Asw[2][BM * BK];   // 2 x 8 KB
    __shared__ ushort_t Bsw[2][BN * BK];   // 2 x 8 KB

    const int t  = threadIdx.x;
    const int w  = t >> 6;
    const int l  = t & 63;
    const int lm = l & 15;
    const int lq = l >> 4;
    const int r0 = blockIdx.x * BM;
    const size_t kc0 = (size_t)blockIdx.y * KCH;

    auto stage = [&](int bi, size_t kb) {
#pragma unroll
        for (int q = 0; q < 2; ++q) {
            const int i = q * 256 + t;
            const int r = i >> 3, s = i & 7;
            gload16(Abf + (size_t)(r0 + r) * N_ATOMS + kb + ((s ^ (r & 7)) << 3),
                    &Asw[bi][(q * 256 + w * 64) * 8]);
        }
#pragma unroll
        for (int q = 0; q < 2; ++q) {
            const int i = q * 256 + t;
            const int r = i >> 3, s = i & 7;
            gload16(hT + (size_t)r * N_ATOMS + kb + ((s ^ (r & 7)) << 3),
                    &Bsw[bi][(q * 256 + w * 64) * 8]);
        }
    };

    f32x4 acc[4];
#pragma unroll
    for (int n = 0; n < 4; ++n) acc[n] = (f32x4){0.f, 0.f, 0.f, 0.f};

    stage(0, kc0);   // 4 loads in flight

    for (int ks = 0; ks < NSTEP; ++ks) {
        const int bi = ks & 1;
        if (ks + 1 < NSTEP) {
            stage(bi ^ 1, kc0 + (size_t)(ks + 1) * BK);       // +4 newest
            asm volatile("s_waitcnt vmcnt(4)" ::: "memory");  // cur's 4 done
        } else {
            asm volatile("s_waitcnt vmcnt(0)" ::: "memory");
        }
        __builtin_amdgcn_s_barrier();                         // B1: buf[bi] readable
        asm volatile("" ::: "memory");
#pragma unroll
        for (int kki = 0; kki < 2; ++kki) {
            const int sx = ((kki * 4 + lq) ^ (lm & 7)) << 3;
            const int ra = w * 16 + lm;
            short8v a0 = *(const short8v*)&Asw[bi][ra * BK + sx];
            short8v b0 = *(const short8v*)&Bsw[bi][(lm)      * BK + sx];
            short8v b1 = *(const short8v*)&Bsw[bi][(lm + 16) * BK + sx];
            short8v b2 = *(const short8v*)&Bsw[bi][(lm + 32) * BK + sx];
            short8v b3 = *(const short8v*)&Bsw[bi][(lm + 48) * BK + sx];
            acc[0] = __builtin_amdgcn_mfma_f32_16x16x32_bf16(a0, b0, acc[0], 0, 0, 0);
            acc[1] = __builtin_amdgcn_mfma_f32_16x16x32_bf16(a0, b1, acc[1], 0, 0, 0);
            acc[2] = __builtin_amdgcn_mfma_f32_16x16x32_bf16(a0, b2, acc[2], 0, 0, 0);
            acc[3] = __builtin_amdgcn_mfma_f32_16x16x32_bf16(a0, b3, acc[3], 0, 0, 0);
        }
        asm volatile("" ::: "memory");
        __builtin_amdgcn_s_barrier();                         // B2: reads of buf[bi] done
        asm volatile("" ::: "memory");
    }

    // C/D layout: col = lane&15, row = (lane>>4)*4 + reg  [m89 verified]
    const int rb = r0 + w * 16 + lq * 4;
#pragma unroll
    for (int j = 0; j < 4; ++j) {
        float* vp = vnext + (size_t)(rb + j) * DIM + lm;
#pragma unroll
        for (int n = 0; n < 4; ++n) atomicAdd(vp + n * 16, acc[n][j]);
    }
}

extern "C" void kernel_launch(void* const* d_in, const int* in_sizes, int n_in,
                              void* d_out, int out_size, void* d_ws, size_t ws_size,
                              hipStream_t stream) {
    const int*   fp    = (const int*)d_in[0];
    const float* A     = (const float*)d_in[1];
    const int*   seg   = (const int*)d_in[2];
    const float* table = (const float*)d_in[3];
    const float* W     = (const float*)d_in[4];
    const float* b     = (const float*)d_in[5];
    float* out = (float*)d_out;

    char* ws = (char*)d_ws;
    float*    vA    = (float*)    ws;                         // 2 MB
    float*    vB    = (float*)   (ws + 2097152);              // 2 MB
    ushort_t* hT    = (ushort_t*)(ws + 4194304);              // 1 MB
    float*    SAf32 = (float*)   (ws + 5242880);              // 8 MB
    ushort_t* SAbf  = (ushort_t*)(ws + 13631488);             // 4 MB
    ushort_t* Abf   = (ushort_t*)(ws + 17825792);             // 134 MB

    (void)hipMemsetAsync(SAf32, 0, (size_t)N_MOL * N_ATOMS * 4, stream);
    (void)hipMemsetAsync(out, 0, (size_t)out_size * 4, stream);

    dim3 mmgrid(N_ATOMS / BM, KS);

    // layer 0: vA = h0; then one pass over f32 A: vA += A@h0, Abf, SAf32
    fused_linear_kernel<1, 0><<<N_ATOMS / 32, 256, 0, stream>>>(
        fp, table, nullptr, seg, W, b, vA, hT, nullptr);
    matmul_cvtsa_kernel<<<mmgrid, 256, 0, stream>>>(A, seg, Abf, SAf32, hT, vA);
    packsa_kernel<<<(N_MOL * N_ATOMS) / (256 * 8), 256, 0, stream>>>(SAf32, SAbf);
    // layer 1: vB = h1, vB += A@h1
    fused_linear_kernel<0, 0><<<N_ATOMS / 32, 256, 0, stream>>>(
        fp, table, vA, seg, W + DIM * DIM, b + DIM, vB, hT, nullptr);
    matmul_mfma_kernel<<<mmgrid, 256, 0, stream>>>(Abf, hT, vB);
    // layer 2: h2 -> hT + segsum(h2) atomically into out
    fused_linear_kernel<0, 1><<<N_ATOMS / 32, 256, 0, stream>>>(
        fp, table, vB, seg, W + 2 * DIM * DIM, b + 2 * DIM, nullptr, hT, out);
    // telescoped final matmul: out += (S*A) @ h2
    matmul_mfma_kernel<<<dim3(N_MOL / BM, KS), 256, 0, stream>>>(SAbf, hT, out);
}